// Round 1
// baseline (550.455 us; speedup 1.0000x reference)
//
#include <hip/hip_runtime.h>
#include <hip/hip_bf16.h>
#include <math.h>

// Problem constants: pred/target are (2,2,128,128,128) fp32 -> 4 volumes of 128^3.
#define NVOL   4
#define N128   128
#define VOL    2097152      // 128^3
#define NTOT   8388608      // 4 * 128^3
#define BIGF   1e12f
#define NB_RED 1024

// ---------------------------------------------------------------------------
// Pass over X (contiguous axis), fused with mask binarization.
// 2 lines per 256-thread block. In-place impossible here since we read src;
// writes go to g (scratch).
// ---------------------------------------------------------------------------
__global__ void pass_x_mask(const float* __restrict__ src, float* __restrict__ g) {
    __shared__ float s[2][N128];
    const int l = threadIdx.x >> 7;     // which line within block
    const int x = threadIdx.x & 127;
    const size_t base = ((size_t)blockIdx.x * 2 + l) * N128;
    float v = src[base + x];
    s[l][x] = (v >= 0.5f) ? BIGF : 0.0f;
    __syncthreads();
    const float xf = (float)x;
    float m0 = 3.4e38f, m1 = 3.4e38f;
    #pragma unroll 8
    for (int y = 0; y < N128; y += 2) {
        float d0 = xf - (float)y;
        float d1 = xf - (float)(y + 1);
        m0 = fminf(m0, fmaf(d0, d0, s[l][y]));
        m1 = fminf(m1, fmaf(d1, d1, s[l][y + 1]));
    }
    g[base + x] = fminf(m0, m1);
}

// ---------------------------------------------------------------------------
// Pass over a strided axis (Y: stride 128, or Z: stride 128*128), in-place.
// Tile = full 128-line extent x 32 contiguous x-columns, staged in LDS.
// grid = NVOL * 128 (fixed coord) * 4 (x tiles) = 2048 blocks of 256 threads.
// ---------------------------------------------------------------------------
template<int LINE_STRIDE, int FIXED_STRIDE>
__global__ void pass_strided(float* __restrict__ g) {
    __shared__ float s[N128 * 32];
    const int xt = blockIdx.x & 3;          // x tile (0..3)
    const int f  = (blockIdx.x >> 2) & 127; // fixed coordinate
    const int b  = blockIdx.x >> 9;         // volume (0..3)
    const size_t base = (size_t)b * VOL + (size_t)f * FIXED_STRIDE + (size_t)xt * 32;
    const int x = threadIdx.x & 31;
    const int lsub = threadIdx.x >> 5;      // 0..7

    // load tile (coalesced in x)
    #pragma unroll
    for (int l0 = 0; l0 < N128; l0 += 8) {
        int l = l0 + lsub;
        s[l * 32 + x] = g[base + (size_t)l * LINE_STRIDE + x];
    }
    __syncthreads();

    // each thread: 16 outputs along the line for its x column
    #pragma unroll 1
    for (int r = 0; r < 16; ++r) {
        const int lo = lsub + r * 8;
        const float lof = (float)lo;
        float m0 = 3.4e38f, m1 = 3.4e38f;
        #pragma unroll 8
        for (int y = 0; y < N128; y += 2) {
            float d0 = lof - (float)y;
            float d1 = lof - (float)(y + 1);
            m0 = fminf(m0, fmaf(d0, d0, s[y * 32 + x]));
            m1 = fminf(m1, fmaf(d1, d1, s[(y + 1) * 32 + x]));
        }
        g[base + (size_t)lo * LINE_STRIDE + x] = fminf(m0, m1);
    }
}

// ---------------------------------------------------------------------------
// Reduction: sum of (pred-target)^2 * (sqrt(g))^2 into per-block double partials.
// ---------------------------------------------------------------------------
__global__ void reduce_kernel(const float* __restrict__ pred,
                              const float* __restrict__ target,
                              const float* __restrict__ g,
                              double* __restrict__ partials) {
    double sum = 0.0;
    const size_t stride = (size_t)gridDim.x * blockDim.x;
    for (size_t i = (size_t)blockIdx.x * blockDim.x + threadIdx.x; i < NTOT; i += stride) {
        float e = pred[i] - target[i];
        float dt = sqrtf(g[i]);     // mimic reference: sqrt then ^2
        sum += (double)((e * e) * (dt * dt));
    }
    // wave(64) shuffle reduce
    for (int off = 32; off > 0; off >>= 1) sum += __shfl_down(sum, off, 64);
    __shared__ double sw[4];
    const int lane = threadIdx.x & 63, w = threadIdx.x >> 6;
    if (lane == 0) sw[w] = sum;
    __syncthreads();
    if (threadIdx.x == 0) partials[blockIdx.x] = sw[0] + sw[1] + sw[2] + sw[3];
}

// ---------------------------------------------------------------------------
// Final: sum 2*NB_RED partials, divide by N, apply is_average, write scalar.
// ---------------------------------------------------------------------------
__global__ void final_kernel(const double* __restrict__ parts,
                             const int* __restrict__ is_avg,
                             float* __restrict__ out) {
    double sum = 0.0;
    for (int i = threadIdx.x; i < 2 * NB_RED; i += 256) sum += parts[i];
    for (int off = 32; off > 0; off >>= 1) sum += __shfl_down(sum, off, 64);
    __shared__ double sw[4];
    const int lane = threadIdx.x & 63, w = threadIdx.x >> 6;
    if (lane == 0) sw[w] = sum;
    __syncthreads();
    if (threadIdx.x == 0) {
        double loss = (sw[0] + sw[1] + sw[2] + sw[3]) / (double)NTOT;
        if (*is_avg == 0) loss *= 2.0;  // * pred.shape[0]
        out[0] = (float)loss;
    }
}

extern "C" void kernel_launch(void* const* d_in, const int* in_sizes, int n_in,
                              void* d_out, int out_size, void* d_ws, size_t ws_size,
                              hipStream_t stream) {
    const float* pred   = (const float*)d_in[0];
    const float* target = (const float*)d_in[1];
    const int*   is_avg = (const int*)d_in[2];
    float* out = (float*)d_out;

    float*  g     = (float*)d_ws;                                   // 32 MB scratch volume
    double* parts = (double*)((char*)d_ws + (size_t)NTOT * sizeof(float));

    const int lines_x_blocks = (NVOL * N128 * N128) / 2;  // 32768 blocks, 2 lines each
    const int strided_blocks = NVOL * N128 * 4;           // 2048

    for (int which = 0; which < 2; ++which) {
        const float* src = which ? target : pred;
        // pass over X (axis 4) fused with binarization
        pass_x_mask<<<lines_x_blocks, 256, 0, stream>>>(src, g);
        // pass over Y (axis 3): line stride 128, fixed coord z stride 128*128
        pass_strided<N128, N128 * N128><<<strided_blocks, 256, 0, stream>>>(g);
        // pass over Z (axis 2): line stride 128*128, fixed coord y stride 128
        pass_strided<N128 * N128, N128><<<strided_blocks, 256, 0, stream>>>(g);
        // accumulate sum((pred-target)^2 * dt^2) for this tensor
        reduce_kernel<<<NB_RED, 256, 0, stream>>>(pred, target, g, parts + which * NB_RED);
    }
    final_kernel<<<1, 256, 0, stream>>>(parts, is_avg, out);
}

// Round 2
// 275.443 us; speedup vs baseline: 1.9984x; 1.9984x over previous
//
#include <hip/hip_runtime.h>
#include <hip/hip_bf16.h>
#include <math.h>

// pred/target: (2,2,128,128,128) fp32 -> 4 volumes of 128^3.
#define NVOL   4
#define N128   128
#define VOL    2097152      // 128^3
#define NTOT   8388608      // 4 * 128^3
#define BIGF   1e12f
#define NB_STR 2048         // blocks per strided pass

// ---------------------------------------------------------------------------
// Pass over X (contiguous axis): input is binary after thresholding, so the
// exact 1-D squared EDT is (distance to nearest zero voxel)^2. Compute via
// ballot bitmasks + clz/ctz: O(1) per voxel, bitwise-exact vs brute force
// (all squared distances are integers < 2^24; empty line -> exactly 1e12,
// matching fp32 rounding of 1e12 + d^2 since d^2 < 32768 = half-ulp(1e12)).
// Block = 256 threads = 2 lines.
// ---------------------------------------------------------------------------
__global__ void pass_x_mask(const float* __restrict__ src, float* __restrict__ g) {
    const int tid = threadIdx.x;
    const int l = tid >> 7;          // line within block
    const int x = tid & 127;
    const int h = (tid >> 6) & 1;    // which 64-lane half of the line
    const size_t base = ((size_t)blockIdx.x * 2 + l) * N128;
    float v = src[base + x];
    // zeros (background) = !(v >= 0.5) — matches reference mask semantics incl. NaN
    unsigned long long zb = __ballot(!(v >= 0.5f));
    __shared__ unsigned long long zm[2][2];
    if ((tid & 63) == 0) zm[l][h] = zb;
    __syncthreads();
    const unsigned long long w0 = zm[l][0], w1 = zm[l][1];
    int dl = 1 << 20, dr = 1 << 20;
    if (x < 64) {
        unsigned long long low = w0 & ((x == 63) ? ~0ull : ((1ull << (x + 1)) - 1ull));
        if (low) dl = x - (63 - __clzll((long long)low));
        unsigned long long hi = w0 >> x;
        if (hi) dr = __ffsll((long long)hi) - 1;
        else if (w1) dr = (64 - x) + (__ffsll((long long)w1) - 1);
    } else {
        const int xl = x - 64;
        unsigned long long low1 = w1 & ((xl == 63) ? ~0ull : ((1ull << (xl + 1)) - 1ull));
        if (low1) dl = xl - (63 - __clzll((long long)low1));
        else if (w0) dl = x - (63 - __clzll((long long)w0));
        unsigned long long hi = w1 >> xl;
        if (hi) dr = __ffsll((long long)hi) - 1;
    }
    const int d = min(dl, dr);
    g[base + x] = (d > 300) ? BIGF : (float)(d * d);
}

// ---------------------------------------------------------------------------
// Strided pass (Y: stride 128, Z: stride 128*128). Tile = 128 lines x 32
// x-columns in LDS. h[y] = g[y] + y^2 stored at load; inner loop:
// c = fma(-2*lo, y, h[y]); out = min_y(c) + lo^2. Exact-integer arithmetic
// keeps this bitwise identical to the naive form (see pass_x comment for the
// BIG/1e12 rounding argument). FUSED: epilogue computes the loss partial
// instead of writing g.
// ---------------------------------------------------------------------------
template<int LINE_STRIDE, int FIXED_STRIDE, bool FUSED>
__global__ void pass_strided(float* __restrict__ g,
                             const float* __restrict__ pred,
                             const float* __restrict__ targ,
                             double* __restrict__ partials) {
    __shared__ float s[N128 * 32];
    const int xt = blockIdx.x & 3;           // x tile (0..3)
    const int f  = (blockIdx.x >> 2) & 127;  // fixed coordinate
    const int b  = blockIdx.x >> 9;          // volume (0..3)
    const size_t base = (size_t)b * VOL + (size_t)f * FIXED_STRIDE + (size_t)xt * 32;
    const int x = threadIdx.x & 31;
    const int lsub = threadIdx.x >> 5;       // 0..7

    // load tile (coalesced in x), fusing the +y^2 term
    #pragma unroll
    for (int l0 = 0; l0 < N128; l0 += 8) {
        const int l = l0 + lsub;
        s[l * 32 + x] = g[base + (size_t)l * LINE_STRIDE + x] + (float)(l * l);
    }
    __syncthreads();

    float m[16], na[16];
    #pragma unroll
    for (int r = 0; r < 16; ++r) {
        m[r] = 3.4e38f;
        na[r] = -2.0f * (float)(lsub + r * 8);
    }

    #pragma unroll 4
    for (int y = 0; y < N128; y += 2) {
        const float h0 = s[y * 32 + x];
        const float h1 = s[(y + 1) * 32 + x];
        const float y0 = (float)y, y1 = (float)(y + 1);
        #pragma unroll
        for (int r = 0; r < 16; ++r) {
            const float c0 = fmaf(na[r], y0, h0);
            const float c1 = fmaf(na[r], y1, h1);
            m[r] = fminf(fminf(c0, c1), m[r]);   // -> v_min3_f32
        }
    }

    if (!FUSED) {
        #pragma unroll
        for (int r = 0; r < 16; ++r) {
            const int lo = lsub + r * 8;
            g[base + (size_t)lo * LINE_STRIDE + x] = m[r] + (float)(lo * lo);
        }
    } else {
        double sum = 0.0;
        #pragma unroll
        for (int r = 0; r < 16; ++r) {
            const int lo = lsub + r * 8;
            const float out = m[r] + (float)(lo * lo);
            const size_t idx = base + (size_t)lo * LINE_STRIDE + x;
            const float dt = sqrtf(out);          // mimic reference sqrt -> ^2
            const float e = pred[idx] - targ[idx];
            sum += (double)((e * e) * (dt * dt));
        }
        for (int off = 32; off > 0; off >>= 1) sum += __shfl_down(sum, off, 64);
        __shared__ double sw[4];
        const int lane = threadIdx.x & 63, w = threadIdx.x >> 6;
        if (lane == 0) sw[w] = sum;
        __syncthreads();
        if (threadIdx.x == 0) partials[blockIdx.x] = sw[0] + sw[1] + sw[2] + sw[3];
    }
}

// ---------------------------------------------------------------------------
// Final: sum 2*NB_STR partial doubles, divide by N, apply is_average.
// ---------------------------------------------------------------------------
__global__ void final_kernel(const double* __restrict__ parts,
                             const int* __restrict__ is_avg,
                             float* __restrict__ out) {
    double sum = 0.0;
    for (int i = threadIdx.x; i < 2 * NB_STR; i += 256) sum += parts[i];
    for (int off = 32; off > 0; off >>= 1) sum += __shfl_down(sum, off, 64);
    __shared__ double sw[4];
    const int lane = threadIdx.x & 63, w = threadIdx.x >> 6;
    if (lane == 0) sw[w] = sum;
    __syncthreads();
    if (threadIdx.x == 0) {
        double loss = (sw[0] + sw[1] + sw[2] + sw[3]) / (double)NTOT;
        if (*is_avg == 0) loss *= 2.0;  // * pred.shape[0]
        out[0] = (float)loss;
    }
}

extern "C" void kernel_launch(void* const* d_in, const int* in_sizes, int n_in,
                              void* d_out, int out_size, void* d_ws, size_t ws_size,
                              hipStream_t stream) {
    const float* pred   = (const float*)d_in[0];
    const float* target = (const float*)d_in[1];
    const int*   is_avg = (const int*)d_in[2];
    float* out = (float*)d_out;

    float*  g     = (float*)d_ws;                                   // 32 MB scratch
    double* parts = (double*)((char*)d_ws + (size_t)NTOT * sizeof(float));

    const int lines_x_blocks = (NVOL * N128 * N128) / 2;  // 32768

    for (int which = 0; which < 2; ++which) {
        const float* src = which ? target : pred;
        pass_x_mask<<<lines_x_blocks, 256, 0, stream>>>(src, g);
        // Y pass: line stride 128, fixed coord = z (stride 16384)
        pass_strided<N128, N128 * N128, false><<<NB_STR, 256, 0, stream>>>(g, nullptr, nullptr, nullptr);
        // Z pass fused with reduction: line stride 16384, fixed coord = y (stride 128)
        pass_strided<N128 * N128, N128, true><<<NB_STR, 256, 0, stream>>>(
            g, pred, target, parts + which * NB_STR);
    }
    final_kernel<<<1, 256, 0, stream>>>(parts, is_avg, out);
}